// Round 4
// baseline (410.176 us; speedup 1.0000x reference)
//
#include <hip/hip_runtime.h>
#include <hip/hip_bf16.h>

// out[b,t,n,f] = in[b,t,n,f] * 1.1 if n < set_size[b,t] else 0
// B=32, T=64, N=128, F=256, fp32. Memory-bound streaming with ragged row mask.
//
// R3 -> R4: load-balance. Previously 1 block per (b,t) with the full grid
// statically resident (2048 blk = 8/CU); block cost varies 2:1 with set_size,
// so the slowest CU (~+10-20%) set the finish time. Now: flat grid-stride over
// the global float4 index space; each thread samples 32 bt's spread 64 apart,
// making per-thread work near-uniform. A wave's 64 consecutive float4 span
// exactly one n-row -> mask branch stays wave-uniform. sizes[bt] is a
// same-address L1-broadcast load (16 KB table), hidden under the stream.

typedef float vfloat4 __attribute__((ext_vector_type(4)));

#define TOTAL_F4 (32 * 64 * 128 * 64)   // B*T*N*(F/4) = 16,777,216
#define BLOCK 256
#define GRID 2048                       // 524288 threads -> 32 iters/thread
#define SCALE 1.1f                      // ALPHA + BETA

__global__ __launch_bounds__(BLOCK) void mask_scale_kernel(
    const vfloat4* __restrict__ in,
    const int* __restrict__ sizes,
    vfloat4* __restrict__ out) {
    const int tid = blockIdx.x * BLOCK + threadIdx.x;
    const int stride = GRID * BLOCK;

#pragma unroll 4
    for (int j = tid; j < TOTAL_F4; j += stride) {
        const int bt = j >> 13;               // j / (N*F/4) = j / 8192
        const int n = (j >> 6) & 127;         // row within (b,t)
        vfloat4 v = (vfloat4)(0.f);
        if (n < sizes[bt]) {                  // wave-uniform (64 f4 = 1 row)
            v = __builtin_nontemporal_load(&in[j]);
            v *= SCALE;
        }
        __builtin_nontemporal_store(v, &out[j]);
    }
}

extern "C" void kernel_launch(void* const* d_in, const int* in_sizes, int n_in,
                              void* d_out, int out_size, void* d_ws, size_t ws_size,
                              hipStream_t stream) {
    const vfloat4* in = (const vfloat4*)d_in[0];
    const int* sizes = (const int*)d_in[1];
    vfloat4* out = (vfloat4*)d_out;

    mask_scale_kernel<<<GRID, BLOCK, 0, stream>>>(in, sizes, out);
}